// Round 15
// baseline (925.710 us; speedup 1.0000x reference)
//
#include <hip/hip_runtime.h>
#include <math.h>

// Problem constants
#define B_    8
#define T_    12
#define BT    96          // B*T
#define NN    500
#define DD    512
#define KK    1024        // 2*D
#define SK    35          // SAMPLE_K == n_top
#define MROWS 48000       // BT*NN

typedef __bf16 bf16x8 __attribute__((ext_vector_type(8)));
typedef float f32x4 __attribute__((ext_vector_type(4)));
typedef unsigned short u16;
typedef unsigned int u32;
typedef u16 ushort8_t __attribute__((ext_vector_type(8)));
typedef u16 ushort4_t __attribute__((ext_vector_type(4)));

__device__ __forceinline__ u16 bf_hi(float x) {
  __bf16 h = (__bf16)x;
  return __builtin_bit_cast(u16, h);
}
__device__ __forceinline__ float bf_tof(u16 b) {
  unsigned int u = ((unsigned int)b) << 16;
  return __builtin_bit_cast(float, u);
}

// conflict-free LDS swizzle (r9-verified: SQ_LDS_BANK_CONFLICT = 0)
__device__ __forceinline__ int lds_off(int row, int kq) {
  return row * 32 + ((kq ^ ((row >> 1) & 3)) * 8);
}

// async global->LDS, 16B per lane; LDS dest = wave-uniform base + lane*16
__device__ __forceinline__ void gload_lds16(const u16* g, u16* l) {
  __builtin_amdgcn_global_load_lds(
      (const __attribute__((address_space(1))) u32*)g,
      (__attribute__((address_space(3))) u32*)l, 16, 0, 0);
}

// ---------------------------------------------------------------------------
// convA: [X|STE] f32 -> Ah, Al bf16 hi/lo, row-major [48000][1024].
// Ah lives in d_out (exact 98,304,000 B fit; dead until attn pO overlay);
// Al lives in the v region (exact fit; dead before proj_v writes v).
// ---------------------------------------------------------------------------
__global__ __launch_bounds__(256) void convA_kernel(
    const float* __restrict__ X, const float* __restrict__ STE,
    u16* __restrict__ Ah, u16* __restrict__ Al)
{
  const int r = blockIdx.x * 2 + (threadIdx.x >> 7);
  const int c0 = (threadIdx.x & 127) * 8;
  const float* src = (c0 < 512)
      ? (X + (size_t)r * 512 + c0)
      : (STE + (size_t)r * 512 + (c0 - 512));
  float4 x0 = *(const float4*)src;
  float4 x1 = *(const float4*)(src + 4);
  float xs[8] = {x0.x, x0.y, x0.z, x0.w, x1.x, x1.y, x1.z, x1.w};
  ushort8_t hi, lo;
#pragma unroll
  for (int j = 0; j < 8; ++j) {
    u16 h = bf_hi(xs[j]);
    hi[j] = h;
    lo[j] = bf_hi(xs[j] - bf_tof(h));
  }
  const size_t o = (size_t)r * 1024 + c0;
  *(ushort8_t*)(Ah + o) = hi;
  *(ushort8_t*)(Al + o) = lo;
}

// ---------------------------------------------------------------------------
// W -> W^T split into bf16 hi/lo:  Bt[n][k] = W[k][n]
// ---------------------------------------------------------------------------
__global__ __launch_bounds__(256) void convW_kernel(
    const float* __restrict__ W, u16* __restrict__ Bth, u16* __restrict__ Btl)
{
  const int n = blockIdx.x;          // 0..511
  const int k0 = threadIdx.x * 4;    // 0..1020
  float xs[4];
#pragma unroll
  for (int j = 0; j < 4; ++j) xs[j] = W[(size_t)(k0 + j) * 512 + n];
  ushort4_t hi, lo;
#pragma unroll
  for (int j = 0; j < 4; ++j) {
    u16 h = bf_hi(xs[j]);
    hi[j] = h;
    lo[j] = bf_hi(xs[j] - bf_tof(h));
  }
  *(ushort4_t*)(Bth + (size_t)n * 1024 + k0) = hi;
  *(ushort4_t*)(Btl + (size_t)n * 1024 + k0) = lo;
}

// ---------------------------------------------------------------------------
// MFMA projection GEMM.  PASSES==3 -> q,k;  PASSES==1 -> v.
// ALL operands pre-converted bf16, ALL staged via global_load_lds with
// pre-swizzled source (r12-proven).  2-phase double-buffer (r14): stage
// next K-step, compute current, ONE barrier.  The step body consumes NO
// global-load result (no cvt!) — prefetches span the full MFMA cluster.
// BM=BN=128, BK=32, 4 waves.  LDS 64 KB (P3) / 32 KB (P1).
// 1-D grid 1500, col-inner decode + bijective XCD swizzle.
// ---------------------------------------------------------------------------
template<int PASSES>
__global__ __launch_bounds__(256) void mfma_proj(
    const u16* __restrict__ Ah, const u16* __restrict__ Al,
    const u16* __restrict__ Bth, const u16* __restrict__ Btl,
    const float* __restrict__ bias, float* __restrict__ out)
{
  constexpr int NT = (PASSES == 3) ? 4 : 2;
  __shared__ u16 ldsbuf[2 * NT * 4096];
  const int tid = threadIdx.x;
  const int lane = tid & 63;
  const int wid = tid >> 6;
  const int wm = wid >> 1, wn = wid & 1;
  // bijective XCD swizzle over nwg=1500 (q=187, r=4)
  const int orig = blockIdx.x;
  const int xcd = orig & 7, pos = orig >> 3;
  const int wg = (xcd < 4 ? xcd * 188 : 752 + (xcd - 4) * 187) + pos;
  const int r0 = (wg >> 2) * 128;
  const int c0 = (wg & 3) * 128;
  const int fr = lane & 15, fk = lane >> 4;
  const int rin = lane >> 2;          // row within a 16-row chunk
  const int qq  = lane & 3;           // quad within row (16B units)

  f32x4 acc[4][4];
#pragma unroll
  for (int m = 0; m < 4; ++m)
#pragma unroll
    for (int n = 0; n < 4; ++n) acc[m][n] = f32x4{0.f, 0.f, 0.f, 0.f};

  // stage K-step kt into buffer `buf` — pure async copies, no VALU cvt
  auto STAGE = [&](int buf, int kt) {
    u16* bAh = ldsbuf + buf * NT * 4096;
    u16* bBh = bAh + 4096;
    u16* bAl = bAh + 8192;   // PASSES==3 only
    u16* bBl = bAh + 12288;  // PASSES==3 only
    const int kk0 = kt * 32;
#pragma unroll
    for (int i = 0; i < 2; ++i) {
      const int ch = wid * 2 + i;           // 0..7
      const int row = ch * 16 + rin;
      const int kq = qq ^ ((row >> 1) & 3);
      const int off = kk0 + kq * 8;
      const size_t ga = (size_t)(r0 + row) * 1024 + off;
      const size_t gb = (size_t)(c0 + row) * 1024 + off;
      gload_lds16(Ah + ga, bAh + ch * 512);
      gload_lds16(Bth + gb, bBh + ch * 512);
      if (PASSES == 3) {
        gload_lds16(Al + ga, bAl + ch * 512);
        gload_lds16(Btl + gb, bBl + ch * 512);
      }
    }
  };

  STAGE(0, 0);
  __syncthreads();
  int cur = 0;
  for (int kt = 0; kt < 32; ++kt) {
    if (kt + 1 < 32) STAGE(cur ^ 1, kt + 1);
    u16* bAh = ldsbuf + cur * NT * 4096;
    u16* bBh = bAh + 4096;
    u16* bAl = bAh + 8192;
    u16* bBl = bAh + 12288;
    bf16x8 ah[4], al[4];
#pragma unroll
    for (int m = 0; m < 4; ++m) {
      const int off = lds_off(wm * 64 + m * 16 + fr, fk);
      ah[m] = *(const bf16x8*)&bAh[off];
      if (PASSES == 3) al[m] = *(const bf16x8*)&bAl[off];
    }
#pragma unroll
    for (int n = 0; n < 4; ++n) {
      const int off = lds_off(wn * 64 + n * 16 + fr, fk);
      bf16x8 bh = *(const bf16x8*)&bBh[off];
      bf16x8 bl;
      if (PASSES == 3) bl = *(const bf16x8*)&bBl[off];
#pragma unroll
      for (int m = 0; m < 4; ++m) {
        acc[m][n] = __builtin_amdgcn_mfma_f32_16x16x32_bf16(
            ah[m], bh, acc[m][n], 0, 0, 0);
        if (PASSES == 3) {
          acc[m][n] = __builtin_amdgcn_mfma_f32_16x16x32_bf16(
              ah[m], bl, acc[m][n], 0, 0, 0);
          acc[m][n] = __builtin_amdgcn_mfma_f32_16x16x32_bf16(
              al[m], bh, acc[m][n], 0, 0, 0);
        }
      }
    }
    __syncthreads();   // single barrier/step
    cur ^= 1;
  }

#pragma unroll
  for (int n = 0; n < 4; ++n) {
    const int col = c0 + wn * 64 + n * 16 + fr;
    const float bb = bias[col];
#pragma unroll
    for (int m = 0; m < 4; ++m) {
      const int rowb = r0 + wm * 64 + m * 16 + fk * 4;
#pragma unroll
      for (int r = 0; r < 4; ++r)
        out[(size_t)(rowb + r) * 512 + col] = fmaxf(acc[m][n][r] + bb, 0.f);
    }
  }
}

// ---------------------------------------------------------------------------
// K2: M[n] = max_s(q[n]·k[sidx]) - sum_s(...)/NN.  One wave per row,
// XCD-pinned (proven r5).
// ---------------------------------------------------------------------------
__global__ __launch_bounds__(256) void sampled_M_kernel(
    const float* __restrict__ q, const float* __restrict__ k,
    const int* __restrict__ sidx, float* __restrict__ Mout)
{
  const int tid = threadIdx.x;
  const int lane = tid & 63, wid = tid >> 6;
  const int bid = blockIdx.x;               // 0..11999
  const int xcd = bid & 7, j = bid >> 3;    // j 0..1499
  const int btg = j / 125, ub = j - btg * 125;
  const int bt = btg * 8 + xcd;
  const int nn = ub * 4 + wid;              // 0..499
  const int n = bt * NN + nn;
  const float* qrow = q + (size_t)n * DD + lane * 8;
  float4 q0 = *(const float4*)qrow;
  float4 q1 = *(const float4*)(qrow + 4);
  const float* kbase = k + (size_t)bt * NN * DD;
  float mx = -INFINITY, sm = 0.f;
  for (int s = 0; s < SK; ++s) {
    int m = sidx[nn * SK + s];
    const float* krow = kbase + (size_t)m * DD + lane * 8;
    float4 k0 = *(const float4*)krow;
    float4 k1 = *(const float4*)(krow + 4);
    float ss = q0.x*k0.x + q0.y*k0.y + q0.z*k0.z + q0.w*k0.w
             + q1.x*k1.x + q1.y*k1.y + q1.z*k1.z + q1.w*k1.w;
#pragma unroll
    for (int off = 32; off > 0; off >>= 1) ss += __shfl_xor(ss, off);
    mx = fmaxf(mx, ss);
    sm += ss;
  }
  if (lane == 0) Mout[n] = mx - sm * (1.0f / (float)NN);
}

// ---------------------------------------------------------------------------
// K3: top-35 (stable ties -> smaller index) + qi-sorted (qi,u) permutation.
// ---------------------------------------------------------------------------
__global__ __launch_bounds__(256) void topk_kernel(
    const float* __restrict__ Mb, int* __restrict__ idxb,
    int* __restrict__ sqi, int* __restrict__ su)
{
  const int bt = blockIdx.x;
  const int tid = threadIdx.x;
  __shared__ float mv[NN];
  __shared__ float rv[256];
  __shared__ int ri[256];
  __shared__ int qsel[SK];
  for (int n = tid; n < NN; n += 256) mv[n] = Mb[(size_t)bt * NN + n];
  __syncthreads();
  for (int it = 0; it < SK; ++it) {
    float bv = -INFINITY; int bi = NN;
    for (int n = tid; n < NN; n += 256) {
      float x = mv[n];
      if (x > bv) { bv = x; bi = n; }
    }
    rv[tid] = bv; ri[tid] = bi;
    __syncthreads();
    for (int sft = 128; sft > 0; sft >>= 1) {
      if (tid < sft) {
        float xv = rv[tid + sft]; int xi = ri[tid + sft];
        if (xv > rv[tid] || (xv == rv[tid] && xi < ri[tid])) {
          rv[tid] = xv; ri[tid] = xi;
        }
      }
      __syncthreads();
    }
    if (tid == 0) {
      idxb[bt * SK + it] = ri[0];
      qsel[it] = ri[0];
      mv[ri[0]] = -INFINITY;
    }
    __syncthreads();
  }
  if (tid < SK) {
    int myqi = qsel[tid];
    int rank = 0;
    for (int j = 0; j < SK; ++j) rank += (qsel[j] < myqi);
    sqi[bt * SK + rank] = myqi;
    su[bt * SK + rank] = tid;
  }
}

// ---------------------------------------------------------------------------
// K4a: flash-split attention partials (r7-proven).
// ---------------------------------------------------------------------------
__global__ __launch_bounds__(256) void attn_part_kernel(
    const float* __restrict__ q, const float* __restrict__ k,
    const float* __restrict__ v, const int* __restrict__ sqi,
    float* __restrict__ pO, float* __restrict__ pm, float* __restrict__ pl)
{
  const int bid = blockIdx.x;               // 0..3359
  const int xcd = bid & 7, j = bid >> 3;    // j 0..419
  const int btg = j / 35, rem = j - btg * 35;
  const int g = rem / 5, c = rem % 5;
  const int bt = btg * 8 + xcd;
  const int base = bt * SK + g * 5;
  const int c0 = c * 100;
  const int tid = threadIdx.x;
  const int lane = tid & 63, wid = tid >> 6;

  __shared__ float sc[5][100];
  __shared__ int qg[5];
  __shared__ float pmx[5], psm[5];
  if (tid < 5) qg[tid] = sqi[base + tid];
  __syncthreads();
  const int gq = qg[4];
  const int mend = (gq < c0 + 99) ? gq : (c0 + 99);   // inclusive

  float4 qr[5][2];
#pragma unroll
  for (int jj = 0; jj < 5; ++jj) {
    const float* qp = q + ((size_t)bt * NN + qg[jj]) * DD + lane * 8;
    qr[jj][0] = *(const float4*)qp;
    qr[jj][1] = *(const float4*)(qp + 4);
  }
  const float scale = 0.044194173824159216f;   // 1/sqrt(512)

  for (int m = c0 + wid; m <= mend; m += 4) {
    const float* krow = k + ((size_t)bt * NN + m) * DD + lane * 8;
    float4 k0 = *(const float4*)krow;
    float4 k1 = *(const float4*)(krow + 4);
    float p[5];
#pragma unroll
    for (int jj = 0; jj < 5; ++jj) {
      p[jj] = qr[jj][0].x*k0.x + qr[jj][0].y*k0.y
            + qr[jj][0].z*k0.z + qr[jj][0].w*k0.w
            + qr[jj][1].x*k1.x + qr[jj][1].y*k1.y
            + qr[jj][1].z*k1.z + qr[jj][1].w*k1.w;
    }
#pragma unroll
    for (int off = 32; off > 0; off >>= 1)
#pragma unroll
      for (int jj = 0; jj < 5; ++jj) p[jj] += __shfl_xor(p[jj], off);
    if (lane == 0) {
#pragma unroll
      for (int jj = 0; jj < 5; ++jj) sc[jj][m - c0] = p[jj] * scale;
    }
  }
  __syncthreads();

  for (int jj = wid; jj < 5; jj += 4) {
    const int qe = (qg[jj] < c0 + 99) ? qg[jj] : (c0 + 99);
    const int len = qe - c0 + 1;
    float mx = -3e38f;
    for (int i = lane; i < len; i += 64) mx = fmaxf(mx, sc[jj][i]);
#pragma unroll
    for (int off = 32; off > 0; off >>= 1) mx = fmaxf(mx, __shfl_xor(mx, off));
    float sm = 0.f;
    for (int i = lane; i < len; i += 64) {
      float e = __expf(sc[jj][i] - mx);
      sc[jj][i] = e;
      sm += e;
    }
#pragma unroll
    for (int off = 32; off > 0; off >>= 1) sm += __shfl_xor(sm, off);
    if (lane == 0) { pmx[jj] = mx; psm[jj] = sm; }
  }
  __syncthreads();

  float a0[5] = {0.f,0.f,0.f,0.f,0.f}, a1[5] = {0.f,0.f,0.f,0.f,0.f};
  const float* vb = v + (size_t)bt * NN * DD;
  for (int m = c0; m <= mend; ++m) {
    float v0 = vb[(size_t)m * DD + tid];
    float v1 = vb[(size_t)m * DD + tid + 256];
#pragma unroll
    for (int jj = 0; jj < 5; ++jj) {
      if (m <= qg[jj]) {
        float w = sc[jj][m - c0];
        a0[jj] = fmaf(w, v0, a0[jj]);
        a1[jj] = fmaf(w, v1, a1[jj]);
      }
    }
  }

  const int pidx = (bt * 7 + g) * 5 + c;
  if (tid < 5) {
    pm[pidx * 5 + tid] = pmx[tid];
    pl[pidx * 5 + tid] = psm[tid];
  }
#pragma unroll
  for (int jj = 0; jj < 5; ++jj) {
    float* po = pO + ((size_t)(pidx * 5 + jj)) * DD;
    po[tid] = a0[jj];
    po[tid + 256] = a1[jj];
  }
}

// ---------------------------------------------------------------------------
// K4b: combine the 5 chunk partials per (bt, sorted-slot s) -> ctx_new.
// ---------------------------------------------------------------------------
__global__ __launch_bounds__(512) void attn_combine_kernel(
    const float* __restrict__ pO, const float* __restrict__ pm,
    const float* __restrict__ pl, const int* __restrict__ su,
    float* __restrict__ ctxn)
{
  const int bid = blockIdx.x;       // bt*35 + s
  const int bt = bid / SK, s = bid % SK;
  const int g = s / 5, jj = s % 5;
  const int d = threadIdx.x;
  __shared__ float w[5];
  __shared__ float linv;
  if (d == 0) {
    float m_[5], l_[5], mx = -3e38f;
#pragma unroll
    for (int c = 0; c < 5; ++c) {
      const int pidx = (bt * 7 + g) * 5 + c;
      m_[c] = pm[pidx * 5 + jj];
      l_[c] = pl[pidx * 5 + jj];
      mx = fmaxf(mx, m_[c]);
    }
    float lt = 0.f;
#pragma unroll
    for (int c = 0; c < 5; ++c) {
      float wc = __expf(m_[c] - mx);
      w[c] = wc;
      lt += wc * l_[c];
    }
    linv = 1.f / lt;
  }
  __syncthreads();
  float o = 0.f;
#pragma unroll
  for (int c = 0; c < 5; ++c) {
    const int pidx = (bt * 7 + g) * 5 + c;
    o = fmaf(w[c], pO[((size_t)(pidx * 5 + jj)) * DD + d], o);
  }
  const int u = su[bt * SK + s];
  ctxn[((size_t)bt * SK + u) * DD + d] = o * linv;
}

// ---------------------------------------------------------------------------
// K5a: per-chunk V sums (chunk = 50 rows).  grid (10, 96), 512 thr.
// ---------------------------------------------------------------------------
__global__ __launch_bounds__(512) void vchunk_sum_kernel(
    const float* __restrict__ v, float* __restrict__ csum)
{
  const int ch = blockIdx.x, bt = blockIdx.y;
  const int d = threadIdx.x;
  const float* vb = v + ((size_t)bt * NN + ch * 50) * DD + d;
  float s = 0.f;
  for (int n = 0; n < 50; ++n) s += vb[(size_t)n * DD];
  csum[((size_t)bt * 10 + ch) * DD + d] = s;
}

// ---------------------------------------------------------------------------
// K5b: prefixed cumsum + scatter + transposed store.  grid (10, 96), 512 thr.
// ---------------------------------------------------------------------------
__global__ __launch_bounds__(512) void cumsum_scatter2_kernel(
    const float* __restrict__ v, const int* __restrict__ idxb,
    const float* __restrict__ ctxn, const float* __restrict__ csum,
    float* __restrict__ out)
{
  const int ch = blockIdx.x, bt = blockIdx.y;
  const int b = bt / T_, t = bt % T_;
  const int d = threadIdx.x;
  const int n0 = ch * 50;
  __shared__ int sel[50];
  if (threadIdx.x < 50) sel[threadIdx.x] = -1;
  __syncthreads();
  if (threadIdx.x < SK) {
    int qi = idxb[bt * SK + threadIdx.x];
    if (qi >= n0 && qi < n0 + 50) sel[qi - n0] = threadIdx.x;
  }
  __syncthreads();
  float s = 0.f;
  for (int c = 0; c < ch; ++c) s += csum[((size_t)bt * 10 + c) * DD + d];
  for (int i = 0; i < 50; ++i) {
    s += v[((size_t)bt * NN + n0 + i) * DD + d];
    float o = s;
    int u = sel[i];
    if (u >= 0) o = ctxn[((size_t)bt * SK + u) * DD + d];
    out[(((size_t)b * NN + (n0 + i)) * T_ + t) * DD + d] = o;
  }
}

// ---------------------------------------------------------------------------
extern "C" void kernel_launch(void* const* d_in, const int* in_sizes, int n_in,
                              void* d_out, int out_size, void* d_ws, size_t ws_size,
                              hipStream_t stream) {
  const float* X   = (const float*)d_in[0];
  const float* STE = (const float*)d_in[1];
  const float* Wq  = (const float*)d_in[2];
  const float* bq  = (const float*)d_in[3];
  const float* Wk  = (const float*)d_in[4];
  const float* bk  = (const float*)d_in[5];
  const float* Wv  = (const float*)d_in[6];
  const float* bv  = (const float*)d_in[7];
  const int* sidx  = (const int*)d_in[8];
  float* out = (float*)d_out;

  // workspace: q | k | v | M | idx | ctx_new | B splits  (~308.4 MB, proven)
  float* q    = (float*)d_ws;
  float* k    = q + (size_t)MROWS * DD;
  float* v    = k + (size_t)MROWS * DD;
  float* Mb   = v + (size_t)MROWS * DD;          // 48,000 f32
  int*   idxb = (int*)(Mb + MROWS);              // 3,360 i32
  float* ctxn = (float*)(idxb + BT * SK);        // 1,720,320 f32
  u16* Bqh = (u16*)(ctxn + (size_t)BT * SK * DD);
  u16* Bql = Bqh + (size_t)512 * 1024;
  u16* Bkh = Bql + (size_t)512 * 1024;
  u16* Bkl = Bkh + (size_t)512 * 1024;
  u16* Bvh = Bkl + (size_t)512 * 1024;
  u16* Bvl = Bvh + (size_t)512 * 1024;
  // overlays on the B-split region (dead after the proj kernels):
  float* csum = (float*)Bqh;                     // 96*10*512 f32 (Bqh+Bql)
  int*   sqi  = (int*)Bkh;                       // 3360 i32
  int*   su   = sqi + BT * SK;                   // 3360 i32
  float* pm   = (float*)(su + BT * SK);          // 3360*5 f32
  float* pl   = pm + 3360 * 5;                   // 3360*5 f32
  // A hi/lo overlays (zero ws growth, exact fits):
  //   Ah -> d_out (98,304,000 B; dead until attn pO overlay)
  //   Al -> v region (98,304,000 B; dead before proj_v writes v)
  u16* Ah = (u16*)d_out;
  u16* Al = (u16*)v;
  // attention O-partials live in d_out (after proj kernels, Ah dead):
  float* pO   = (float*)d_out;                   // 3360*5*512 f32 = 34.4 MB
  (void)ws_size; (void)in_sizes; (void)n_in; (void)out_size;

  convA_kernel<<<MROWS / 2, 256, 0, stream>>>(X, STE, Ah, Al);
  convW_kernel<<<512, 256, 0, stream>>>(Wq, Bqh, Bql);
  convW_kernel<<<512, 256, 0, stream>>>(Wk, Bkh, Bkl);
  convW_kernel<<<512, 256, 0, stream>>>(Wv, Bvh, Bvl);

  mfma_proj<3><<<1500, 256, 0, stream>>>(Ah, Al, Bqh, Bql, bq, q);
  mfma_proj<3><<<1500, 256, 0, stream>>>(Ah, Al, Bkh, Bkl, bk, k);
  // proj_v reads only Ah; it overwrites the Al region with v (Al dead here)
  mfma_proj<1><<<1500, 256, 0, stream>>>(Ah, Al, Bvh, Bvl, bv, v);

  sampled_M_kernel<<<12000, 256, 0, stream>>>(q, k, sidx, Mb);
  topk_kernel<<<BT, 256, 0, stream>>>(Mb, idxb, sqi, su);
  attn_part_kernel<<<3360, 256, 0, stream>>>(q, k, v, sqi, pO, pm, pl);
  attn_combine_kernel<<<3360, 512, 0, stream>>>(pO, pm, pl, su, ctxn);
  dim3 g5(10, BT);
  vchunk_sum_kernel<<<g5, 512, 0, stream>>>(v, csum);
  cumsum_scatter2_kernel<<<g5, 512, 0, stream>>>(v, idxb, ctxn, csum, out);
}

// Round 16
// 884.948 us; speedup vs baseline: 1.0461x; 1.0461x over previous
//
#include <hip/hip_runtime.h>
#include <math.h>

// Problem constants
#define B_    8
#define T_    12
#define BT    96          // B*T
#define NN    500
#define DD    512
#define KK    1024        // 2*D
#define SK    35          // SAMPLE_K == n_top
#define MROWS 48000       // BT*NN

typedef __bf16 bf16x8 __attribute__((ext_vector_type(8)));
typedef float f32x4 __attribute__((ext_vector_type(4)));
typedef unsigned short u16;
typedef unsigned int u32;
typedef u16 ushort8_t __attribute__((ext_vector_type(8)));
typedef u16 ushort4_t __attribute__((ext_vector_type(4)));

__device__ __forceinline__ u16 bf_hi(float x) {
  __bf16 h = (__bf16)x;
  return __builtin_bit_cast(u16, h);
}
__device__ __forceinline__ float bf_tof(u16 b) {
  unsigned int u = ((unsigned int)b) << 16;
  return __builtin_bit_cast(float, u);
}

// conflict-free LDS swizzle (r9-verified: SQ_LDS_BANK_CONFLICT = 0)
__device__ __forceinline__ int lds_off(int row, int kq) {
  return row * 32 + ((kq ^ ((row >> 1) & 3)) * 8);
}

// async global->LDS, 16B per lane; LDS dest = wave-uniform base + lane*16
__device__ __forceinline__ void gload_lds16(const u16* g, u16* l) {
  __builtin_amdgcn_global_load_lds(
      (const __attribute__((address_space(1))) u32*)g,
      (__attribute__((address_space(3))) u32*)l, 16, 0, 0);
}

// ---------------------------------------------------------------------------
// W -> W^T split into bf16 hi/lo:  Bt[n][k] = W[k][n]
// ---------------------------------------------------------------------------
__global__ __launch_bounds__(256) void convW_kernel(
    const float* __restrict__ W, u16* __restrict__ Bth, u16* __restrict__ Btl)
{
  const int n = blockIdx.x;          // 0..511
  const int k0 = threadIdx.x * 4;    // 0..1020
  float xs[4];
#pragma unroll
  for (int j = 0; j < 4; ++j) xs[j] = W[(size_t)(k0 + j) * 512 + n];
  ushort4_t hi, lo;
#pragma unroll
  for (int j = 0; j < 4; ++j) {
    u16 h = bf_hi(xs[j]);
    hi[j] = h;
    lo[j] = bf_hi(xs[j] - bf_tof(h));
  }
  *(ushort4_t*)(Bth + (size_t)n * 1024 + k0) = hi;
  *(ushort4_t*)(Btl + (size_t)n * 1024 + k0) = lo;
}

// ---------------------------------------------------------------------------
// MFMA projection GEMM (r14-proven, 903 µs total).  PASSES==3 -> q,k;
// PASSES==1 -> v.  128x128, 4 waves; B via global_load_lds pre-swizzled-src;
// A reg-cvt-staged; 2-phase double-buffer, ONE barrier per K-step.
// ---------------------------------------------------------------------------
template<int PASSES>
__global__ __launch_bounds__(256) void mfma_proj(
    const float* __restrict__ X, const float* __restrict__ STE,
    const u16* __restrict__ Bth, const u16* __restrict__ Btl,
    const float* __restrict__ bias, float* __restrict__ out)
{
  constexpr int NT = (PASSES == 3) ? 4 : 2;
  __shared__ u16 ldsbuf[2 * NT * 4096];
  const int tid = threadIdx.x;
  const int lane = tid & 63;
  const int wid = tid >> 6;
  const int wm = wid >> 1, wn = wid & 1;
  // bijective XCD swizzle over nwg=1500 (q=187, r=4)
  const int orig = blockIdx.x;
  const int xcd = orig & 7, pos = orig >> 3;
  const int wg = (xcd < 4 ? xcd * 188 : 752 + (xcd - 4) * 187) + pos;
  const int r0 = (wg >> 2) * 128;
  const int c0 = (wg & 3) * 128;
  const int fr = lane & 15, fk = lane >> 4;
  const int rin = lane >> 2;          // row within a 16-row chunk
  const int qq  = lane & 3;           // quad within row (16B units)

  f32x4 acc[4][4];
#pragma unroll
  for (int m = 0; m < 4; ++m)
#pragma unroll
    for (int n = 0; n < 4; ++n) acc[m][n] = f32x4{0.f, 0.f, 0.f, 0.f};

  // stage K-step kt into buffer `buf`
  auto STAGE = [&](int buf, int kt) {
    u16* bAh = ldsbuf + buf * NT * 4096;
    u16* bBh = bAh + 4096;
    u16* bAl = bAh + 8192;   // PASSES==3 only
    u16* bBl = bAh + 12288;  // PASSES==3 only
    const int kk0 = kt * 32;
    // A global loads FIRST (their vmcnt wait must not drain B's loads)
    float4 a0[2], a1[2];
#pragma unroll
    for (int p = 0; p < 2; ++p) {
      const int c = tid + p * 256;
      const int row = c >> 2, kc = c & 3;
      const int col = kk0 + kc * 8;
      const float* src = (col < 512)
          ? (X + (size_t)(r0 + row) * 512 + col)
          : (STE + (size_t)(r0 + row) * 512 + (col - 512));
      a0[p] = *(const float4*)src;
      a1[p] = *(const float4*)(src + 4);
    }
    // B: async global_load_lds (stays in flight across the MFMA cluster)
#pragma unroll
    for (int i = 0; i < 2; ++i) {
      const int ch = wid * 2 + i;           // 0..7
      const int row = ch * 16 + rin;
      const int kq = qq ^ ((row >> 1) & 3);
      const size_t gb = (size_t)(c0 + row) * 1024 + kk0 + kq * 8;
      gload_lds16(Bth + gb, bBh + ch * 512);
      if (PASSES == 3) gload_lds16(Btl + gb, bBl + ch * 512);
    }
    // A cvt + swizzled ds_write
#pragma unroll
    for (int p = 0; p < 2; ++p) {
      const int c = tid + p * 256;
      const int row = c >> 2, kc = c & 3;
      const int dst = lds_off(row, kc);
      float xs[8] = {a0[p].x, a0[p].y, a0[p].z, a0[p].w,
                     a1[p].x, a1[p].y, a1[p].z, a1[p].w};
      ushort8_t hi, lo;
#pragma unroll
      for (int j = 0; j < 8; ++j) {
        u16 h = bf_hi(xs[j]);
        hi[j] = h;
        if (PASSES == 3) lo[j] = bf_hi(xs[j] - bf_tof(h));
      }
      *(ushort8_t*)&bAh[dst] = hi;
      if (PASSES == 3) *(ushort8_t*)&bAl[dst] = lo;
    }
  };

  STAGE(0, 0);
  __syncthreads();
  int cur = 0;
  for (int kt = 0; kt < 32; ++kt) {
    if (kt + 1 < 32) STAGE(cur ^ 1, kt + 1);
    u16* bAh = ldsbuf + cur * NT * 4096;
    u16* bBh = bAh + 4096;
    u16* bAl = bAh + 8192;
    u16* bBl = bAh + 12288;
    bf16x8 ah[4], al[4];
#pragma unroll
    for (int m = 0; m < 4; ++m) {
      const int off = lds_off(wm * 64 + m * 16 + fr, fk);
      ah[m] = *(const bf16x8*)&bAh[off];
      if (PASSES == 3) al[m] = *(const bf16x8*)&bAl[off];
    }
#pragma unroll
    for (int n = 0; n < 4; ++n) {
      const int off = lds_off(wn * 64 + n * 16 + fr, fk);
      bf16x8 bh = *(const bf16x8*)&bBh[off];
      bf16x8 bl;
      if (PASSES == 3) bl = *(const bf16x8*)&bBl[off];
#pragma unroll
      for (int m = 0; m < 4; ++m) {
        acc[m][n] = __builtin_amdgcn_mfma_f32_16x16x32_bf16(
            ah[m], bh, acc[m][n], 0, 0, 0);
        if (PASSES == 3) {
          acc[m][n] = __builtin_amdgcn_mfma_f32_16x16x32_bf16(
              ah[m], bl, acc[m][n], 0, 0, 0);
          acc[m][n] = __builtin_amdgcn_mfma_f32_16x16x32_bf16(
              al[m], bh, acc[m][n], 0, 0, 0);
        }
      }
    }
    __syncthreads();   // single barrier/step
    cur ^= 1;
  }

#pragma unroll
  for (int n = 0; n < 4; ++n) {
    const int col = c0 + wn * 64 + n * 16 + fr;
    const float bb = bias[col];
#pragma unroll
    for (int m = 0; m < 4; ++m) {
      const int rowb = r0 + wm * 64 + m * 16 + fk * 4;
#pragma unroll
      for (int r = 0; r < 4; ++r)
        out[(size_t)(rowb + r) * 512 + col] = fmaxf(acc[m][n][r] + bb, 0.f);
    }
  }
}

// ---------------------------------------------------------------------------
// K2: M[n] = max_s(q[n]·k[sidx]) - sum_s(...)/NN.  One wave per row,
// XCD-pinned.  r15 diagnosis: latency-bound (VALUBusy 38%, Occ 82%) on the
// serial per-sample chain {sidx load -> k gather -> 6 dependent shfl}.
// Fix: sidx preloaded to LDS; sample loop UNROLLED x5 (35 = 5x7) -> 10
// independent k-loads issued up front + 5 interleaved shuffle chains.
// ---------------------------------------------------------------------------
__global__ __launch_bounds__(256) void sampled_M_kernel(
    const float* __restrict__ q, const float* __restrict__ k,
    const int* __restrict__ sidx, float* __restrict__ Mout)
{
  const int tid = threadIdx.x;
  const int lane = tid & 63, wid = tid >> 6;
  const int bid = blockIdx.x;               // 0..11999
  const int xcd = bid & 7, j = bid >> 3;    // j 0..1499
  const int btg = j / 125, ub = j - btg * 125;
  const int bt = btg * 8 + xcd;
  __shared__ int sIdx[4][SK];
  if (tid < 4 * SK) {
    const int w = tid / SK, s = tid - w * SK;
    sIdx[w][s] = sidx[(ub * 4 + w) * SK + s];
  }
  __syncthreads();
  const int nn = ub * 4 + wid;              // 0..499
  const int n = bt * NN + nn;
  const float* qrow = q + (size_t)n * DD + lane * 8;
  float4 q0 = *(const float4*)qrow;
  float4 q1 = *(const float4*)(qrow + 4);
  const float* kbase = k + (size_t)bt * NN * DD + lane * 8;
  float mx = -INFINITY, sm = 0.f;
  for (int s0 = 0; s0 < SK; s0 += 5) {
    float p[5];
#pragma unroll
    for (int u = 0; u < 5; ++u) {
      const float* krow = kbase + (size_t)sIdx[wid][s0 + u] * DD;
      float4 k0 = *(const float4*)krow;
      float4 k1 = *(const float4*)(krow + 4);
      p[u] = q0.x*k0.x + q0.y*k0.y + q0.z*k0.z + q0.w*k0.w
           + q1.x*k1.x + q1.y*k1.y + q1.z*k1.z + q1.w*k1.w;
    }
#pragma unroll
    for (int off = 32; off > 0; off >>= 1)
#pragma unroll
      for (int u = 0; u < 5; ++u) p[u] += __shfl_xor(p[u], off);
#pragma unroll
    for (int u = 0; u < 5; ++u) { mx = fmaxf(mx, p[u]); sm += p[u]; }
  }
  if (lane == 0) Mout[n] = mx - sm * (1.0f / (float)NN);
}

// ---------------------------------------------------------------------------
// K3: top-35 (stable ties -> smaller index) + qi-sorted (qi,u) permutation.
// ---------------------------------------------------------------------------
__global__ __launch_bounds__(256) void topk_kernel(
    const float* __restrict__ Mb, int* __restrict__ idxb,
    int* __restrict__ sqi, int* __restrict__ su)
{
  const int bt = blockIdx.x;
  const int tid = threadIdx.x;
  __shared__ float mv[NN];
  __shared__ float rv[256];
  __shared__ int ri[256];
  __shared__ int qsel[SK];
  for (int n = tid; n < NN; n += 256) mv[n] = Mb[(size_t)bt * NN + n];
  __syncthreads();
  for (int it = 0; it < SK; ++it) {
    float bv = -INFINITY; int bi = NN;
    for (int n = tid; n < NN; n += 256) {
      float x = mv[n];
      if (x > bv) { bv = x; bi = n; }
    }
    rv[tid] = bv; ri[tid] = bi;
    __syncthreads();
    for (int sft = 128; sft > 0; sft >>= 1) {
      if (tid < sft) {
        float xv = rv[tid + sft]; int xi = ri[tid + sft];
        if (xv > rv[tid] || (xv == rv[tid] && xi < ri[tid])) {
          rv[tid] = xv; ri[tid] = xi;
        }
      }
      __syncthreads();
    }
    if (tid == 0) {
      idxb[bt * SK + it] = ri[0];
      qsel[it] = ri[0];
      mv[ri[0]] = -INFINITY;
    }
    __syncthreads();
  }
  if (tid < SK) {
    int myqi = qsel[tid];
    int rank = 0;
    for (int j = 0; j < SK; ++j) rank += (qsel[j] < myqi);
    sqi[bt * SK + rank] = myqi;
    su[bt * SK + rank] = tid;
  }
}

// ---------------------------------------------------------------------------
// K4a: flash-split attention partials (r7-proven).
// ---------------------------------------------------------------------------
__global__ __launch_bounds__(256) void attn_part_kernel(
    const float* __restrict__ q, const float* __restrict__ k,
    const float* __restrict__ v, const int* __restrict__ sqi,
    float* __restrict__ pO, float* __restrict__ pm, float* __restrict__ pl)
{
  const int bid = blockIdx.x;               // 0..3359
  const int xcd = bid & 7, j = bid >> 3;    // j 0..419
  const int btg = j / 35, rem = j - btg * 35;
  const int g = rem / 5, c = rem % 5;
  const int bt = btg * 8 + xcd;
  const int base = bt * SK + g * 5;
  const int c0 = c * 100;
  const int tid = threadIdx.x;
  const int lane = tid & 63, wid = tid >> 6;

  __shared__ float sc[5][100];
  __shared__ int qg[5];
  __shared__ float pmx[5], psm[5];
  if (tid < 5) qg[tid] = sqi[base + tid];
  __syncthreads();
  const int gq = qg[4];
  const int mend = (gq < c0 + 99) ? gq : (c0 + 99);   // inclusive

  float4 qr[5][2];
#pragma unroll
  for (int jj = 0; jj < 5; ++jj) {
    const float* qp = q + ((size_t)bt * NN + qg[jj]) * DD + lane * 8;
    qr[jj][0] = *(const float4*)qp;
    qr[jj][1] = *(const float4*)(qp + 4);
  }
  const float scale = 0.044194173824159216f;   // 1/sqrt(512)

  for (int m = c0 + wid; m <= mend; m += 4) {
    const float* krow = k + ((size_t)bt * NN + m) * DD + lane * 8;
    float4 k0 = *(const float4*)krow;
    float4 k1 = *(const float4*)(krow + 4);
    float p[5];
#pragma unroll
    for (int jj = 0; jj < 5; ++jj) {
      p[jj] = qr[jj][0].x*k0.x + qr[jj][0].y*k0.y
            + qr[jj][0].z*k0.z + qr[jj][0].w*k0.w
            + qr[jj][1].x*k1.x + qr[jj][1].y*k1.y
            + qr[jj][1].z*k1.z + qr[jj][1].w*k1.w;
    }
#pragma unroll
    for (int off = 32; off > 0; off >>= 1)
#pragma unroll
      for (int jj = 0; jj < 5; ++jj) p[jj] += __shfl_xor(p[jj], off);
    if (lane == 0) {
#pragma unroll
      for (int jj = 0; jj < 5; ++jj) sc[jj][m - c0] = p[jj] * scale;
    }
  }
  __syncthreads();

  for (int jj = wid; jj < 5; jj += 4) {
    const int qe = (qg[jj] < c0 + 99) ? qg[jj] : (c0 + 99);
    const int len = qe - c0 + 1;
    float mx = -3e38f;
    for (int i = lane; i < len; i += 64) mx = fmaxf(mx, sc[jj][i]);
#pragma unroll
    for (int off = 32; off > 0; off >>= 1) mx = fmaxf(mx, __shfl_xor(mx, off));
    float sm = 0.f;
    for (int i = lane; i < len; i += 64) {
      float e = __expf(sc[jj][i] - mx);
      sc[jj][i] = e;
      sm += e;
    }
#pragma unroll
    for (int off = 32; off > 0; off >>= 1) sm += __shfl_xor(sm, off);
    if (lane == 0) { pmx[jj] = mx; psm[jj] = sm; }
  }
  __syncthreads();

  float a0[5] = {0.f,0.f,0.f,0.f,0.f}, a1[5] = {0.f,0.f,0.f,0.f,0.f};
  const float* vb = v + (size_t)bt * NN * DD;
  for (int m = c0; m <= mend; ++m) {
    float v0 = vb[(size_t)m * DD + tid];
    float v1 = vb[(size_t)m * DD + tid + 256];
#pragma unroll
    for (int jj = 0; jj < 5; ++jj) {
      if (m <= qg[jj]) {
        float w = sc[jj][m - c0];
        a0[jj] = fmaf(w, v0, a0[jj]);
        a1[jj] = fmaf(w, v1, a1[jj]);
      }
    }
  }

  const int pidx = (bt * 7 + g) * 5 + c;
  if (tid < 5) {
    pm[pidx * 5 + tid] = pmx[tid];
    pl[pidx * 5 + tid] = psm[tid];
  }
#pragma unroll
  for (int jj = 0; jj < 5; ++jj) {
    float* po = pO + ((size_t)(pidx * 5 + jj)) * DD;
    po[tid] = a0[jj];
    po[tid + 256] = a1[jj];
  }
}

// ---------------------------------------------------------------------------
// K4b: combine the 5 chunk partials per (bt, sorted-slot s) -> ctx_new.
// ---------------------------------------------------------------------------
__global__ __launch_bounds__(512) void attn_combine_kernel(
    const float* __restrict__ pO, const float* __restrict__ pm,
    const float* __restrict__ pl, const int* __restrict__ su,
    float* __restrict__ ctxn)
{
  const int bid = blockIdx.x;       // bt*35 + s
  const int bt = bid / SK, s = bid % SK;
  const int g = s / 5, jj = s % 5;
  const int d = threadIdx.x;
  __shared__ float w[5];
  __shared__ float linv;
  if (d == 0) {
    float m_[5], l_[5], mx = -3e38f;
#pragma unroll
    for (int c = 0; c < 5; ++c) {
      const int pidx = (bt * 7 + g) * 5 + c;
      m_[c] = pm[pidx * 5 + jj];
      l_[c] = pl[pidx * 5 + jj];
      mx = fmaxf(mx, m_[c]);
    }
    float lt = 0.f;
#pragma unroll
    for (int c = 0; c < 5; ++c) {
      float wc = __expf(m_[c] - mx);
      w[c] = wc;
      lt += wc * l_[c];
    }
    linv = 1.f / lt;
  }
  __syncthreads();
  float o = 0.f;
#pragma unroll
  for (int c = 0; c < 5; ++c) {
    const int pidx = (bt * 7 + g) * 5 + c;
    o = fmaf(w[c], pO[((size_t)(pidx * 5 + jj)) * DD + d], o);
  }
  const int u = su[bt * SK + s];
  ctxn[((size_t)bt * SK + u) * DD + d] = o * linv;
}

// ---------------------------------------------------------------------------
// K5a: per-chunk V sums (chunk = 50 rows).  grid (10, 96), 512 thr.
// ---------------------------------------------------------------------------
__global__ __launch_bounds__(512) void vchunk_sum_kernel(
    const float* __restrict__ v, float* __restrict__ csum)
{
  const int ch = blockIdx.x, bt = blockIdx.y;
  const int d = threadIdx.x;
  const float* vb = v + ((size_t)bt * NN + ch * 50) * DD + d;
  float s = 0.f;
  for (int n = 0; n < 50; ++n) s += vb[(size_t)n * DD];
  csum[((size_t)bt * 10 + ch) * DD + d] = s;
}

// ---------------------------------------------------------------------------
// K5b: prefixed cumsum + scatter + transposed store.  grid (10, 96), 512 thr.
// ---------------------------------------------------------------------------
__global__ __launch_bounds__(512) void cumsum_scatter2_kernel(
    const float* __restrict__ v, const int* __restrict__ idxb,
    const float* __restrict__ ctxn, const float* __restrict__ csum,
    float* __restrict__ out)
{
  const int ch = blockIdx.x, bt = blockIdx.y;
  const int b = bt / T_, t = bt % T_;
  const int d = threadIdx.x;
  const int n0 = ch * 50;
  __shared__ int sel[50];
  if (threadIdx.x < 50) sel[threadIdx.x] = -1;
  __syncthreads();
  if (threadIdx.x < SK) {
    int qi = idxb[bt * SK + threadIdx.x];
    if (qi >= n0 && qi < n0 + 50) sel[qi - n0] = threadIdx.x;
  }
  __syncthreads();
  float s = 0.f;
  for (int c = 0; c < ch; ++c) s += csum[((size_t)bt * 10 + c) * DD + d];
  for (int i = 0; i < 50; ++i) {
    s += v[((size_t)bt * NN + n0 + i) * DD + d];
    float o = s;
    int u = sel[i];
    if (u >= 0) o = ctxn[((size_t)bt * SK + u) * DD + d];
    out[(((size_t)b * NN + (n0 + i)) * T_ + t) * DD + d] = o;
  }
}

// ---------------------------------------------------------------------------
extern "C" void kernel_launch(void* const* d_in, const int* in_sizes, int n_in,
                              void* d_out, int out_size, void* d_ws, size_t ws_size,
                              hipStream_t stream) {
  const float* X   = (const float*)d_in[0];
  const float* STE = (const float*)d_in[1];
  const float* Wq  = (const float*)d_in[2];
  const float* bq  = (const float*)d_in[3];
  const float* Wk  = (const float*)d_in[4];
  const float* bk  = (const float*)d_in[5];
  const float* Wv  = (const float*)d_in[6];
  const float* bv  = (const float*)d_in[7];
  const int* sidx  = (const int*)d_in[8];
  float* out = (float*)d_out;

  // workspace: q | k | v | M | idx | ctx_new | B splits  (~308.4 MB, proven)
  float* q    = (float*)d_ws;
  float* k    = q + (size_t)MROWS * DD;
  float* v    = k + (size_t)MROWS * DD;
  float* Mb   = v + (size_t)MROWS * DD;          // 48,000 f32
  int*   idxb = (int*)(Mb + MROWS);              // 3,360 i32
  float* ctxn = (float*)(idxb + BT * SK);        // 1,720,320 f32
  u16* Bqh = (u16*)(ctxn + (size_t)BT * SK * DD);
  u16* Bql = Bqh + (size_t)512 * 1024;
  u16* Bkh = Bql + (size_t)512 * 1024;
  u16* Bkl = Bkh + (size_t)512 * 1024;
  u16* Bvh = Bkl + (size_t)512 * 1024;
  u16* Bvl = Bvh + (size_t)512 * 1024;
  // overlays on the B-split region (dead after the proj kernels):
  float* csum = (float*)Bqh;                     // 96*10*512 f32 (Bqh+Bql)
  int*   sqi  = (int*)Bkh;                       // 3360 i32
  int*   su   = sqi + BT * SK;                   // 3360 i32
  float* pm   = (float*)(su + BT * SK);          // 3360*5 f32
  float* pl   = pm + 3360 * 5;                   // 3360*5 f32
  // attention O-partials live in d_out (dead until the final scatter):
  float* pO   = (float*)d_out;                   // 3360*5*512 f32 = 34.4 MB
  (void)ws_size; (void)in_sizes; (void)n_in; (void)out_size;

  convW_kernel<<<512, 256, 0, stream>>>(Wq, Bqh, Bql);
  convW_kernel<<<512, 256, 0, stream>>>(Wk, Bkh, Bkl);
  convW_kernel<<<512, 256, 0, stream>>>(Wv, Bvh, Bvl);

  mfma_proj<3><<<1500, 256, 0, stream>>>(X, STE, Bqh, Bql, bq, q);
  mfma_proj<3><<<1500, 256, 0, stream>>>(X, STE, Bkh, Bkl, bk, k);
  mfma_proj<1><<<1500, 256, 0, stream>>>(X, STE, Bvh, Bvl, bv, v);

  sampled_M_kernel<<<12000, 256, 0, stream>>>(q, k, sidx, Mb);
  topk_kernel<<<BT, 256, 0, stream>>>(Mb, idxb, sqi, su);
  attn_part_kernel<<<3360, 256, 0, stream>>>(q, k, v, sqi, pO, pm, pl);
  attn_combine_kernel<<<3360, 512, 0, stream>>>(pO, pm, pl, su, ctxn);
  dim3 g5(10, BT);
  vchunk_sum_kernel<<<g5, 512, 0, stream>>>(v, csum);
  cumsum_scatter2_kernel<<<g5, 512, 0, stream>>>(v, idxb, ctxn, csum, out);
}